// Round 9
// baseline (362.736 us; speedup 1.0000x reference)
//
#include <hip/hip_runtime.h>
#include <hip/hip_fp16.h>

#define N_NODES 40000
#define N_EDGES 640000
#define DIM 128
#define N_GRAPHS 64
#define BN_EPS 1e-5f
#define AGG_BLOCKS 2048
#define SCAN_NB 40   // ceil(40000/1024)
#define GEMM_NB (N_NODES / 64)   // 625 blocks x 64 rows (exact)

// ---------------- CSR build ----------------
__global__ __launch_bounds__(256) void k_count_edges(const int* __restrict__ ei, int* __restrict__ cnt) {
    int e = blockIdx.x * 256 + threadIdx.x;
    if (e < N_EDGES) atomicAdd(&cnt[ei[N_EDGES + e]], 1);   // dst row
}

// batch is sorted: graph offsets are boundaries (no atomics).
__global__ __launch_bounds__(256) void k_boundaries(const int* __restrict__ batch, int* __restrict__ goff) {
    int n = blockIdx.x * 256 + threadIdx.x;
    if (n >= N_NODES) return;
    int b = batch[n];
    int bp = (n == 0) ? -1 : batch[n - 1];
    for (int g = bp + 1; g <= b; ++g) goff[g] = n;          // rare divergence
    if (n == N_NODES - 1)
        for (int g = b + 1; g <= N_GRAPHS; ++g) goff[g] = N_NODES;
}

// ---- 3-pass parallel exclusive scan of cnt -> off, plus pos/dinv fill ----
__global__ __launch_bounds__(1024) void k_scan_blk(const int* __restrict__ cnt, int* __restrict__ off,
                                                   int* __restrict__ blocksum) {
    __shared__ int sums[1024];
    int i = blockIdx.x * 1024 + threadIdx.x;
    int v = (i < N_NODES) ? cnt[i] : 0;
    sums[threadIdx.x] = v;
    __syncthreads();
    for (int d = 1; d < 1024; d <<= 1) {
        int t = (threadIdx.x >= d) ? sums[threadIdx.x - d] : 0;
        __syncthreads();
        sums[threadIdx.x] += t;
        __syncthreads();
    }
    if (i < N_NODES) off[i] = sums[threadIdx.x] - v;        // exclusive within block
    if (threadIdx.x == 1023) blocksum[blockIdx.x] = sums[1023];
}

__global__ void k_scan_tops(const int* __restrict__ blocksum, int* __restrict__ blockoff) {
    if (threadIdx.x == 0) {
        int run = 0;
        for (int b = 0; b < SCAN_NB; ++b) { blockoff[b] = run; run += blocksum[b]; }
        blockoff[SCAN_NB] = run;
    }
}

__global__ __launch_bounds__(1024) void k_scan_fix(const int* __restrict__ cnt, const int* __restrict__ blockoff,
                                                   int* __restrict__ off, int* __restrict__ pos,
                                                   float* __restrict__ dinv) {
    int i = blockIdx.x * 1024 + threadIdx.x;
    if (i < N_NODES) {
        int o = off[i] + blockoff[blockIdx.x];
        off[i] = o; pos[i] = o;
        dinv[i] = rsqrtf((float)(cnt[i] + 1));              // +1 self loop, always > 0
    }
    if (i == 0) off[N_NODES] = blockoff[SCAN_NB];
}

// one scattered 8B record per edge: {src, coef}
__global__ __launch_bounds__(256) void k_fill(const int* __restrict__ ei, int* __restrict__ pos,
                                              int2* __restrict__ erec, const float* __restrict__ dinv) {
    int e = blockIdx.x * 256 + threadIdx.x;
    if (e < N_EDGES) {
        int s = ei[e];                 // src row
        int d = ei[N_EDGES + e];       // dst row
        int p = atomicAdd(&pos[d], 1);
        float c = dinv[s] * dinv[d];
        erec[p] = make_int2(s, __float_as_int(c));
    }
}

// ---------------- GEMM: out16 = fp16( affine(in) @ W + b ) ----------------
// 64 rows / 128 threads (2 waves) per block; 8x(4+4) per-thread tile.
// LDS: W fp32 (64KB) + transposed fp16 A-tile inlt[k][r] (16KB) = 80KB
// -> 2 blocks/CU (4 waves, one per SIMD). Per k per thread: 3 ds_read_b128
// (all <=2-way bank aliased = free) feeding 64 FMAs.
__global__ __launch_bounds__(128) void k_gemm(const float* __restrict__ in, const float* __restrict__ W,
                                              const float* __restrict__ bias, const float* __restrict__ ac,
                                              __half* __restrict__ out16) {
    __shared__ float  Wl[DIM * DIM];     // 64 KB, row-major [k][c]
    __shared__ __half inlt[DIM * 64];    // 16 KB, transposed [k][r]
    int t = threadIdx.x;
    long row0 = (long)blockIdx.x * 64;

    const float4* W4 = (const float4*)W;
    float4* Wl4 = (float4*)Wl;
#pragma unroll
    for (int i = 0; i < 32; ++i) Wl4[t + i * 128] = W4[t + i * 128];

    {
        int r = t & 63;
        int k4b = (t >> 6) * 16;                       // 0 or 16
        const float4* inrow = (const float4*)(in + (row0 + r) * DIM);
#pragma unroll
        for (int j = 0; j < 16; ++j) {
            int k4 = k4b + j;                          // 0..31
            float4 v = inrow[k4];
            if (ac) {
                int k = k4 * 4;
                v.x = fmaf(ac[k + 0], v.x, ac[DIM + k + 0]);
                v.y = fmaf(ac[k + 1], v.y, ac[DIM + k + 1]);
                v.z = fmaf(ac[k + 2], v.z, ac[DIM + k + 2]);
                v.w = fmaf(ac[k + 3], v.w, ac[DIM + k + 3]);
            }
            int kk = k4 * 4;
            inlt[(kk + 0) * 64 + r] = __float2half(v.x);   // 2B*r: 2-way bank, free
            inlt[(kk + 1) * 64 + r] = __float2half(v.y);
            inlt[(kk + 2) * 64 + r] = __float2half(v.z);
            inlt[(kk + 3) * 64 + r] = __float2half(v.w);
        }
    }
    __syncthreads();

    int ty = t >> 4, tx = t & 15;              // ty 0..7, tx 0..15
    int r0 = ty * 8, c0 = tx * 4;
    float acc[8][8];
#pragma unroll
    for (int i = 0; i < 8; ++i)
#pragma unroll
        for (int j = 0; j < 8; ++j) acc[i][j] = 0.f;

#pragma unroll 4
    for (int k = 0; k < DIM; ++k) {
        float4 raw = *(const float4*)&inlt[k * 64 + r0];   // 16B: 8 halves (8 rows)
        const __half2* h = (const __half2*)&raw;
        float2 f01 = __half22float2(h[0]);
        float2 f23 = __half22float2(h[1]);
        float2 f45 = __half22float2(h[2]);
        float2 f67 = __half22float2(h[3]);
        float av[8] = {f01.x, f01.y, f23.x, f23.y, f45.x, f45.y, f67.x, f67.y};
        float4 wA = *(const float4*)&Wl[k * DIM + c0];
        float4 wB = *(const float4*)&Wl[k * DIM + 64 + c0];
        float wv[8] = {wA.x, wA.y, wA.z, wA.w, wB.x, wB.y, wB.z, wB.w};
#pragma unroll
        for (int i = 0; i < 8; ++i)
#pragma unroll
            for (int j = 0; j < 8; ++j)
                acc[i][j] = fmaf(av[i], wv[j], acc[i][j]);
    }

    float4 bA = *(const float4*)&bias[c0];
    float4 bB = *(const float4*)&bias[64 + c0];
#pragma unroll
    for (int i = 0; i < 8; ++i) {
        long r = row0 + r0 + i;                        // 625*64 == N_NODES: no guard
        __half2* oA = (__half2*)&out16[r * DIM + c0];
        __half2* oB = (__half2*)&out16[r * DIM + 64 + c0];
        oA[0] = __floats2half2_rn(acc[i][0] + bA.x, acc[i][1] + bA.y);
        oA[1] = __floats2half2_rn(acc[i][2] + bA.z, acc[i][3] + bA.w);
        oB[0] = __floats2half2_rn(acc[i][4] + bB.x, acc[i][5] + bB.y);
        oB[1] = __floats2half2_rn(acc[i][6] + bB.z, acc[i][7] + bB.w);
    }
}

// ---------------- Aggregation + ReLU + BN partial stats ----------------
__global__ __launch_bounds__(256) void k_agg(const __half* __restrict__ h16, const int* __restrict__ off,
                                             const int2* __restrict__ erec,
                                             const float* __restrict__ dinv, float* __restrict__ hout,
                                             float* __restrict__ partials) {
    __shared__ float colacc[256];
    colacc[threadIdx.x] = 0.f;
    __syncthreads();

    const __half2* rows = (const __half2*)h16;   // 64 half2 per row
    int lane = threadIdx.x & 63;
    int wid = (blockIdx.x * 256 + threadIdx.x) >> 6;
    const int NW = AGG_BLOCKS * 4;
    float s0 = 0.f, s1 = 0.f, q0 = 0.f, q1 = 0.f;

    for (int i = wid; i < N_NODES; i += NW) {
        float di = dinv[i];
        float selfc = di * di;
        float2 rv = __half22float2(rows[(long)i * 64 + lane]);
        float a0 = rv.x * selfc, a1 = rv.y * selfc;
        int e  = off[i];
        int e1 = off[i + 1];
#pragma unroll 4
        for (; e < e1; ++e) {
            int2 rec = erec[e];
            float c = __int_as_float(rec.y);
            float2 r = __half22float2(rows[(long)rec.x * 64 + lane]);
            a0 = fmaf(r.x, c, a0);
            a1 = fmaf(r.y, c, a1);
        }
        a0 = fmaxf(a0, 0.f);
        a1 = fmaxf(a1, 0.f);
        ((float2*)(hout + (long)i * DIM))[lane] = make_float2(a0, a1);
        s0 += a0; q0 += a0 * a0; s1 += a1; q1 += a1 * a1;
    }

    // partials layout: [0..127] col sums, [128..255] col sumsq (true col idx)
    atomicAdd(&colacc[2 * lane],           s0);
    atomicAdd(&colacc[2 * lane + 1],       s1);
    atomicAdd(&colacc[128 + 2 * lane],     q0);
    atomicAdd(&colacc[128 + 2 * lane + 1], q1);
    __syncthreads();
    partials[(long)blockIdx.x * 256 + threadIdx.x] = colacc[threadIdx.x];
}

// ---------------- BN stats -> affine a,c (8 blocks x 16 cols) ----------------
__global__ __launch_bounds__(1024) void k_stats(const float* __restrict__ partials,
                                                const float* __restrict__ gamma, const float* __restrict__ beta,
                                                float* __restrict__ ac) {
    __shared__ float ls[1024], lq[1024];
    int dd = threadIdx.x & 15;
    int seg = threadIdx.x >> 4;                    // 64 segments
    int d = blockIdx.x * 16 + dd;
    float s = 0.f, q = 0.f;
    for (int b = seg; b < AGG_BLOCKS; b += 64) {
        s += partials[b * 256 + d];
        q += partials[b * 256 + 128 + d];
    }
    ls[threadIdx.x] = s; lq[threadIdx.x] = q;
    __syncthreads();
    for (int off = 512; off >= 16; off >>= 1) {
        if (threadIdx.x < off) {
            ls[threadIdx.x] += ls[threadIdx.x + off];
            lq[threadIdx.x] += lq[threadIdx.x + off];
        }
        __syncthreads();
    }
    if (threadIdx.x < 16) {
        s = ls[threadIdx.x]; q = lq[threadIdx.x];
        float mean = s * (1.f / N_NODES);
        float var  = q * (1.f / N_NODES) - mean * mean;
        float a = gamma[d] * rsqrtf(var + BN_EPS);
        ac[d] = a;
        ac[DIM + d] = fmaf(-mean, a, beta[d]);
    }
}

// ---------------- Pool (applies last BN affine); 8 row-segments/block ----------------
__global__ __launch_bounds__(1024) void k_pool(const float* __restrict__ h, const float* __restrict__ ac,
                                               const int* __restrict__ goff, float* __restrict__ pooled) {
    __shared__ float red[1024];
    int g = blockIdx.x;
    int d = threadIdx.x & 127;
    int seg = threadIdx.x >> 7;                    // 8 segments
    int r0 = goff[g], r1 = goff[g + 1];
    float s = 0.f;
    for (int r = r0 + seg; r < r1; r += 8) s += h[(long)r * DIM + d];
    red[threadIdx.x] = s;
    __syncthreads();
    if (threadIdx.x < 512) red[threadIdx.x] += red[threadIdx.x + 512];
    __syncthreads();
    if (threadIdx.x < 256) red[threadIdx.x] += red[threadIdx.x + 256];
    __syncthreads();
    if (threadIdx.x < 128) {
        s = red[threadIdx.x] + red[threadIdx.x + 128];
        int n = r1 - r0;
        float a = ac[d], c = ac[DIM + d];
        float denom = (float)(n > 0 ? n : 1);
        pooled[g * DIM + d] = (a * s + c * (float)n) / denom;
    }
}

// ---------------- Final MLP ----------------
__global__ __launch_bounds__(64) void k_mlp(const float* __restrict__ pooled, const float* __restrict__ w1,
                                            const float* __restrict__ b1, const float* __restrict__ w2,
                                            const float* __restrict__ b2, float* __restrict__ out) {
    int g = blockIdx.x, j = threadIdx.x;
    const float* p = pooled + g * DIM;
    float h = b1[j];
#pragma unroll
    for (int k = 0; k < DIM; ++k) h = fmaf(p[k], w1[k * 64 + j], h);
    h = fmaxf(h, 0.f);
    float v = h * w2[j];
#pragma unroll
    for (int o = 32; o > 0; o >>= 1) v += __shfl_down(v, o);
    if (j == 0) out[g] = v + b2[0];
}

extern "C" void kernel_launch(void* const* d_in, const int* in_sizes, int n_in,
                              void* d_out, int out_size, void* d_ws, size_t ws_size,
                              hipStream_t stream) {
    const float* x      = (const float*)d_in[0];
    const int*   ei     = (const int*)d_in[1];
    const int*   batch  = (const int*)d_in[2];
    const float* Ws     = (const float*)d_in[3];
    const float* bs     = (const float*)d_in[4];
    const float* gammas = (const float*)d_in[5];
    const float* betas  = (const float*)d_in[6];
    const float* w1     = (const float*)d_in[7];
    const float* b1     = (const float*)d_in[8];
    const float* w2     = (const float*)d_in[9];
    const float* b2     = (const float*)d_in[10];
    float* out = (float*)d_out;

    char* p = (char*)d_ws;
    auto alloc = [&](size_t bytes) { void* r = (void*)p; p += (bytes + 255) & ~(size_t)255; return r; };
    int*    cnt      = (int*)alloc((size_t)N_NODES * 4);
    int*    off      = (int*)alloc((size_t)(N_NODES + 1) * 4);
    int*    pos      = (int*)alloc((size_t)N_NODES * 4);
    int*    goff     = (int*)alloc((size_t)(N_GRAPHS + 1) * 4);
    int*    blocksum = (int*)alloc((size_t)(SCAN_NB + 1) * 4);
    int*    blockoff = (int*)alloc((size_t)(SCAN_NB + 1) * 4);
    int2*   erec     = (int2*)alloc((size_t)N_EDGES * 8);
    float*  dinv     = (float*)alloc((size_t)N_NODES * 4);
    __half* h16      = (__half*)alloc((size_t)N_NODES * DIM * 2);
    float*  hB       = (float*)alloc((size_t)N_NODES * DIM * 4);
    float*  parts    = (float*)alloc((size_t)AGG_BLOCKS * 256 * 4);
    float*  ac       = (float*)alloc(256 * 4);
    float*  pooled   = (float*)alloc((size_t)N_GRAPHS * DIM * 4);

    hipMemsetAsync(cnt, 0, (size_t)N_NODES * 4, stream);

    k_count_edges<<<(N_EDGES + 255) / 256, 256, 0, stream>>>(ei, cnt);
    k_boundaries<<<(N_NODES + 255) / 256, 256, 0, stream>>>(batch, goff);
    k_scan_blk<<<SCAN_NB, 1024, 0, stream>>>(cnt, off, blocksum);
    k_scan_tops<<<1, 64, 0, stream>>>(blocksum, blockoff);
    k_scan_fix<<<SCAN_NB, 1024, 0, stream>>>(cnt, blockoff, off, pos, dinv);
    k_fill<<<(N_EDGES + 255) / 256, 256, 0, stream>>>(ei, pos, erec, dinv);

    const float* cur_in = x;
    const float* cur_ac = nullptr;
    for (int l = 0; l < 3; ++l) {
        k_gemm<<<GEMM_NB, 128, 0, stream>>>(cur_in, Ws + (size_t)l * DIM * DIM, bs + (size_t)l * DIM, cur_ac, h16);
        k_agg<<<AGG_BLOCKS, 256, 0, stream>>>(h16, off, erec, dinv, hB, parts);
        k_stats<<<8, 1024, 0, stream>>>(parts, gammas + (size_t)l * DIM, betas + (size_t)l * DIM, ac);
        cur_in = hB;
        cur_ac = ac;
    }
    k_pool<<<N_GRAPHS, 1024, 0, stream>>>(hB, ac, goff, pooled);
    k_mlp<<<N_GRAPHS, 64, 0, stream>>>(pooled, w1, b1, w2, b2, out);
}

// Round 10
// 314.323 us; speedup vs baseline: 1.1540x; 1.1540x over previous
//
#include <hip/hip_runtime.h>
#include <hip/hip_fp16.h>

#define N_NODES 40000
#define N_EDGES 640000
#define DIM 128
#define N_GRAPHS 64
#define BN_EPS 1e-5f
#define AGG_BLOCKS 2048
#define SCAN_NB 40   // ceil(40000/1024)
#define GEMM_NB (N_NODES / 64)   // 625 blocks x 64 rows (exact)
#define WTP 136                  // padded k-stride for Wt / A tiles (halves)

typedef _Float16 f16x8 __attribute__((ext_vector_type(8)));
typedef float    f32x4 __attribute__((ext_vector_type(4)));

// ---------------- CSR build ----------------
__global__ __launch_bounds__(256) void k_count_edges(const int* __restrict__ ei, int* __restrict__ cnt) {
    int e = blockIdx.x * 256 + threadIdx.x;
    if (e < N_EDGES) atomicAdd(&cnt[ei[N_EDGES + e]], 1);   // dst row
}

// batch is sorted: graph offsets are boundaries (no atomics).
__global__ __launch_bounds__(256) void k_boundaries(const int* __restrict__ batch, int* __restrict__ goff) {
    int n = blockIdx.x * 256 + threadIdx.x;
    if (n >= N_NODES) return;
    int b = batch[n];
    int bp = (n == 0) ? -1 : batch[n - 1];
    for (int g = bp + 1; g <= b; ++g) goff[g] = n;          // rare divergence
    if (n == N_NODES - 1)
        for (int g = b + 1; g <= N_GRAPHS; ++g) goff[g] = N_NODES;
}

// ---- 3-pass parallel exclusive scan of cnt -> off, plus pos/dinv fill ----
__global__ __launch_bounds__(1024) void k_scan_blk(const int* __restrict__ cnt, int* __restrict__ off,
                                                   int* __restrict__ blocksum) {
    __shared__ int sums[1024];
    int i = blockIdx.x * 1024 + threadIdx.x;
    int v = (i < N_NODES) ? cnt[i] : 0;
    sums[threadIdx.x] = v;
    __syncthreads();
    for (int d = 1; d < 1024; d <<= 1) {
        int t = (threadIdx.x >= d) ? sums[threadIdx.x - d] : 0;
        __syncthreads();
        sums[threadIdx.x] += t;
        __syncthreads();
    }
    if (i < N_NODES) off[i] = sums[threadIdx.x] - v;        // exclusive within block
    if (threadIdx.x == 1023) blocksum[blockIdx.x] = sums[1023];
}

__global__ void k_scan_tops(const int* __restrict__ blocksum, int* __restrict__ blockoff) {
    if (threadIdx.x == 0) {
        int run = 0;
        for (int b = 0; b < SCAN_NB; ++b) { blockoff[b] = run; run += blocksum[b]; }
        blockoff[SCAN_NB] = run;
    }
}

__global__ __launch_bounds__(1024) void k_scan_fix(const int* __restrict__ cnt, const int* __restrict__ blockoff,
                                                   int* __restrict__ off, int* __restrict__ pos,
                                                   float* __restrict__ dinv) {
    int i = blockIdx.x * 1024 + threadIdx.x;
    if (i < N_NODES) {
        int o = off[i] + blockoff[blockIdx.x];
        off[i] = o; pos[i] = o;
        dinv[i] = rsqrtf((float)(cnt[i] + 1));              // +1 self loop, always > 0
    }
    if (i == 0) off[N_NODES] = blockoff[SCAN_NB];
}

// one scattered 8B record per edge: {src, coef}
__global__ __launch_bounds__(256) void k_fill(const int* __restrict__ ei, int* __restrict__ pos,
                                              int2* __restrict__ erec, const float* __restrict__ dinv) {
    int e = blockIdx.x * 256 + threadIdx.x;
    if (e < N_EDGES) {
        int s = ei[e];                 // src row
        int d = ei[N_EDGES + e];       // dst row
        int p = atomicAdd(&pos[d], 1);
        float c = dinv[s] * dinv[d];
        erec[p] = make_int2(s, __float_as_int(c));
    }
}

// ---- W prep: per layer, transposed hi/lo fp16 split, padded [c][WTP] ----
// wt layout: [layer][2][128][WTP] halves; W = hi + lo to ~2^-22 rel.
__global__ __launch_bounds__(256) void k_prepw(const float* __restrict__ Ws, __half* __restrict__ wt) {
    int idx = blockIdx.x * 256 + threadIdx.x;        // 3*128*128
    if (idx >= 3 * DIM * DIM) return;
    int l = idx >> 14;
    int rem = idx & 16383;
    int k = rem >> 7;         // row of W
    int c = rem & 127;        // col of W
    float w = Ws[(size_t)l * DIM * DIM + k * DIM + c];
    __half hi = __float2half(w);
    __half lo = __float2half(w - __half2float(hi));
    size_t base = (size_t)l * 2 * DIM * WTP;
    wt[base + (size_t)c * WTP + k] = hi;
    wt[base + (size_t)DIM * WTP + (size_t)c * WTP + k] = lo;
}

// ---------------- GEMM via MFMA: out16 = fp16( affine(in) @ W + b ) -------
// 256 thr / 4 waves / 64 rows per block. LDS: Wt hi+lo (69.6KB) + A (17.4KB).
// Per wave: 4 k-steps x 8 col-tiles x 2 (hi/lo) mfma_f32_16x16x32_f16.
__global__ __launch_bounds__(256) void k_gemm(const float* __restrict__ in, const __half* __restrict__ wt2,
                                              const float* __restrict__ bias, const float* __restrict__ ac,
                                              __half* __restrict__ out16) {
    __shared__ __half Wl2[2 * DIM * WTP];   // hi then lo
    __shared__ __half Al[64 * WTP];
    int t = threadIdx.x;
    long row0 = (long)blockIdx.x * 64;

    {   // stage Wt hi+lo: 2*128*136 halves = 4352 float4
        const float4* src = (const float4*)wt2;
        float4* dst = (float4*)Wl2;
        for (int i = t; i < 4352; i += 256) dst[i] = src[i];
    }
    for (int i = t; i < 2048; i += 256) {   // A: 64 rows x 32 float4
        int r = i >> 5, k4 = i & 31;
        float4 v = ((const float4*)(in + (row0 + r) * DIM))[k4];
        if (ac) {
            int k = k4 * 4;
            v.x = fmaf(ac[k + 0], v.x, ac[DIM + k + 0]);
            v.y = fmaf(ac[k + 1], v.y, ac[DIM + k + 1]);
            v.z = fmaf(ac[k + 2], v.z, ac[DIM + k + 2]);
            v.w = fmaf(ac[k + 3], v.w, ac[DIM + k + 3]);
        }
        __half2* d = (__half2*)&Al[r * WTP + k4 * 4];
        d[0] = __floats2half2_rn(v.x, v.y);
        d[1] = __floats2half2_rn(v.z, v.w);
    }
    __syncthreads();

    int w = t >> 6;            // wave 0..3 -> rows w*16..w*16+15
    int l = t & 63;
    int lr = l & 15;           // A row-in-tile / B col-in-tile / D col
    int lk = (l >> 4) * 8;     // k sub-block

    f32x4 acc[8];
#pragma unroll
    for (int i = 0; i < 8; ++i) acc[i] = (f32x4)(0.f);

#pragma unroll
    for (int ks = 0; ks < 4; ++ks) {
        f16x8 a = *(const f16x8*)&Al[(w * 16 + lr) * WTP + ks * 32 + lk];
#pragma unroll
        for (int tile = 0; tile < 8; ++tile) {
            f16x8 bh = *(const f16x8*)&Wl2[(tile * 16 + lr) * WTP + ks * 32 + lk];
            f16x8 bl = *(const f16x8*)&Wl2[DIM * WTP + (tile * 16 + lr) * WTP + ks * 32 + lk];
            acc[tile] = __builtin_amdgcn_mfma_f32_16x16x32_f16(a, bh, acc[tile], 0, 0, 0);
            acc[tile] = __builtin_amdgcn_mfma_f32_16x16x32_f16(a, bl, acc[tile], 0, 0, 0);
        }
    }

    long orow = row0 + w * 16 + (l >> 4) * 4;   // D: col=l&15, row=(l>>4)*4+i
#pragma unroll
    for (int tile = 0; tile < 8; ++tile) {
        int col = tile * 16 + lr;
        float b = bias[col];
#pragma unroll
        for (int i = 0; i < 4; ++i)
            out16[(orow + i) * DIM + col] = __float2half(acc[tile][i] + b);
    }
}

// ---------------- Aggregation + ReLU + BN partial stats ----------------
__global__ __launch_bounds__(256) void k_agg(const __half* __restrict__ h16, const int* __restrict__ off,
                                             const int2* __restrict__ erec,
                                             const float* __restrict__ dinv, float* __restrict__ hout,
                                             float* __restrict__ partials) {
    __shared__ float colacc[256];
    colacc[threadIdx.x] = 0.f;
    __syncthreads();

    const __half2* rows = (const __half2*)h16;   // 64 half2 per row
    int lane = threadIdx.x & 63;
    int wid = (blockIdx.x * 256 + threadIdx.x) >> 6;
    const int NW = AGG_BLOCKS * 4;
    float s0 = 0.f, s1 = 0.f, q0 = 0.f, q1 = 0.f;

    for (int i = wid; i < N_NODES; i += NW) {
        float di = dinv[i];
        float selfc = di * di;
        float2 rv = __half22float2(rows[(long)i * 64 + lane]);
        float a0 = rv.x * selfc, a1 = rv.y * selfc;
        int e  = off[i];
        int e1 = off[i + 1];
#pragma unroll 4
        for (; e < e1; ++e) {
            int2 rec = erec[e];
            float c = __int_as_float(rec.y);
            float2 r = __half22float2(rows[(long)rec.x * 64 + lane]);
            a0 = fmaf(r.x, c, a0);
            a1 = fmaf(r.y, c, a1);
        }
        a0 = fmaxf(a0, 0.f);
        a1 = fmaxf(a1, 0.f);
        ((float2*)(hout + (long)i * DIM))[lane] = make_float2(a0, a1);
        s0 += a0; q0 += a0 * a0; s1 += a1; q1 += a1 * a1;
    }

    // partials layout: [0..127] col sums, [128..255] col sumsq (true col idx)
    atomicAdd(&colacc[2 * lane],           s0);
    atomicAdd(&colacc[2 * lane + 1],       s1);
    atomicAdd(&colacc[128 + 2 * lane],     q0);
    atomicAdd(&colacc[128 + 2 * lane + 1], q1);
    __syncthreads();
    partials[(long)blockIdx.x * 256 + threadIdx.x] = colacc[threadIdx.x];
}

// ---------------- BN stats -> affine a,c (8 blocks x 16 cols) ----------------
__global__ __launch_bounds__(1024) void k_stats(const float* __restrict__ partials,
                                                const float* __restrict__ gamma, const float* __restrict__ beta,
                                                float* __restrict__ ac) {
    __shared__ float ls[1024], lq[1024];
    int dd = threadIdx.x & 15;
    int seg = threadIdx.x >> 4;                    // 64 segments
    int d = blockIdx.x * 16 + dd;
    float s = 0.f, q = 0.f;
    for (int b = seg; b < AGG_BLOCKS; b += 64) {
        s += partials[b * 256 + d];
        q += partials[b * 256 + 128 + d];
    }
    ls[threadIdx.x] = s; lq[threadIdx.x] = q;
    __syncthreads();
    for (int off = 512; off >= 16; off >>= 1) {
        if (threadIdx.x < off) {
            ls[threadIdx.x] += ls[threadIdx.x + off];
            lq[threadIdx.x] += lq[threadIdx.x + off];
        }
        __syncthreads();
    }
    if (threadIdx.x < 16) {
        s = ls[threadIdx.x]; q = lq[threadIdx.x];
        float mean = s * (1.f / N_NODES);
        float var  = q * (1.f / N_NODES) - mean * mean;
        float a = gamma[d] * rsqrtf(var + BN_EPS);
        ac[d] = a;
        ac[DIM + d] = fmaf(-mean, a, beta[d]);
    }
}

// ---------------- Pool (applies last BN affine); 8 row-segments/block ----------------
__global__ __launch_bounds__(1024) void k_pool(const float* __restrict__ h, const float* __restrict__ ac,
                                               const int* __restrict__ goff, float* __restrict__ pooled) {
    __shared__ float red[1024];
    int g = blockIdx.x;
    int d = threadIdx.x & 127;
    int seg = threadIdx.x >> 7;                    // 8 segments
    int r0 = goff[g], r1 = goff[g + 1];
    float s = 0.f;
    for (int r = r0 + seg; r < r1; r += 8) s += h[(long)r * DIM + d];
    red[threadIdx.x] = s;
    __syncthreads();
    if (threadIdx.x < 512) red[threadIdx.x] += red[threadIdx.x + 512];
    __syncthreads();
    if (threadIdx.x < 256) red[threadIdx.x] += red[threadIdx.x + 256];
    __syncthreads();
    if (threadIdx.x < 128) {
        s = red[threadIdx.x] + red[threadIdx.x + 128];
        int n = r1 - r0;
        float a = ac[d], c = ac[DIM + d];
        float denom = (float)(n > 0 ? n : 1);
        pooled[g * DIM + d] = (a * s + c * (float)n) / denom;
    }
}

// ---------------- Final MLP ----------------
__global__ __launch_bounds__(64) void k_mlp(const float* __restrict__ pooled, const float* __restrict__ w1,
                                            const float* __restrict__ b1, const float* __restrict__ w2,
                                            const float* __restrict__ b2, float* __restrict__ out) {
    int g = blockIdx.x, j = threadIdx.x;
    const float* p = pooled + g * DIM;
    float h = b1[j];
#pragma unroll
    for (int k = 0; k < DIM; ++k) h = fmaf(p[k], w1[k * 64 + j], h);
    h = fmaxf(h, 0.f);
    float v = h * w2[j];
#pragma unroll
    for (int o = 32; o > 0; o >>= 1) v += __shfl_down(v, o);
    if (j == 0) out[g] = v + b2[0];
}

extern "C" void kernel_launch(void* const* d_in, const int* in_sizes, int n_in,
                              void* d_out, int out_size, void* d_ws, size_t ws_size,
                              hipStream_t stream) {
    const float* x      = (const float*)d_in[0];
    const int*   ei     = (const int*)d_in[1];
    const int*   batch  = (const int*)d_in[2];
    const float* Ws     = (const float*)d_in[3];
    const float* bs     = (const float*)d_in[4];
    const float* gammas = (const float*)d_in[5];
    const float* betas  = (const float*)d_in[6];
    const float* w1     = (const float*)d_in[7];
    const float* b1     = (const float*)d_in[8];
    const float* w2     = (const float*)d_in[9];
    const float* b2     = (const float*)d_in[10];
    float* out = (float*)d_out;

    char* p = (char*)d_ws;
    auto alloc = [&](size_t bytes) { void* r = (void*)p; p += (bytes + 255) & ~(size_t)255; return r; };
    int*    cnt      = (int*)alloc((size_t)N_NODES * 4);
    int*    off      = (int*)alloc((size_t)(N_NODES + 1) * 4);
    int*    pos      = (int*)alloc((size_t)N_NODES * 4);
    int*    goff     = (int*)alloc((size_t)(N_GRAPHS + 1) * 4);
    int*    blocksum = (int*)alloc((size_t)(SCAN_NB + 1) * 4);
    int*    blockoff = (int*)alloc((size_t)(SCAN_NB + 1) * 4);
    int2*   erec     = (int2*)alloc((size_t)N_EDGES * 8);
    float*  dinv     = (float*)alloc((size_t)N_NODES * 4);
    __half* wt       = (__half*)alloc((size_t)3 * 2 * DIM * WTP * 2);
    __half* h16      = (__half*)alloc((size_t)N_NODES * DIM * 2);
    float*  hB       = (float*)alloc((size_t)N_NODES * DIM * 4);
    float*  parts    = (float*)alloc((size_t)AGG_BLOCKS * 256 * 4);
    float*  ac       = (float*)alloc(256 * 4);
    float*  pooled   = (float*)alloc((size_t)N_GRAPHS * DIM * 4);

    hipMemsetAsync(cnt, 0, (size_t)N_NODES * 4, stream);

    k_count_edges<<<(N_EDGES + 255) / 256, 256, 0, stream>>>(ei, cnt);
    k_boundaries<<<(N_NODES + 255) / 256, 256, 0, stream>>>(batch, goff);
    k_scan_blk<<<SCAN_NB, 1024, 0, stream>>>(cnt, off, blocksum);
    k_scan_tops<<<1, 64, 0, stream>>>(blocksum, blockoff);
    k_scan_fix<<<SCAN_NB, 1024, 0, stream>>>(cnt, blockoff, off, pos, dinv);
    k_fill<<<(N_EDGES + 255) / 256, 256, 0, stream>>>(ei, pos, erec, dinv);
    k_prepw<<<(3 * DIM * DIM + 255) / 256, 256, 0, stream>>>(Ws, wt);

    const float* cur_in = x;
    const float* cur_ac = nullptr;
    for (int l = 0; l < 3; ++l) {
        k_gemm<<<GEMM_NB, 256, 0, stream>>>(cur_in, wt + (size_t)l * 2 * DIM * WTP,
                                            bs + (size_t)l * DIM, cur_ac, h16);
        k_agg<<<AGG_BLOCKS, 256, 0, stream>>>(h16, off, erec, dinv, hB, parts);
        k_stats<<<8, 1024, 0, stream>>>(parts, gammas + (size_t)l * DIM, betas + (size_t)l * DIM, ac);
        cur_in = hB;
        cur_ac = ac;
    }
    k_pool<<<N_GRAPHS, 1024, 0, stream>>>(hB, ac, goff, pooled);
    k_mlp<<<N_GRAPHS, 64, 0, stream>>>(pooled, w1, b1, w2, b2, out);
}